// Round 7
// baseline (279.146 us; speedup 1.0000x reference)
//
#include <hip/hip_runtime.h>

#define IN_F   128
#define OUT_F  64
#define EPB    4096  // edges per bin block

typedef __attribute__((ext_vector_type(8))) short bf16x8;
typedef __attribute__((ext_vector_type(4))) float f32x4;

// ---- bf16 helpers (RNE) ----
__device__ __forceinline__ unsigned short f2bf(float f) {
    unsigned int u = __float_as_uint(f);
    u += 0x7fffu + ((u >> 16) & 1u);
    return (unsigned short)(u >> 16);
}
__device__ __forceinline__ float bf2f(unsigned short h) {
    return __uint_as_float(((unsigned int)h) << 16);
}

// ---------------- GEMM via MFMA bf16: out[n,o] = sum_k x[n,k]*W[o,k] + b[o] --------------
// Block = 64 rows (4 waves x 16 rows), wave does 16 rows x 64 feats = 16 MFMAs.
// LDS rows padded to 136 ushorts: row stride 68 dwords -> bank shift 4/row -> 2-way
// aliasing on b128 frag reads (free, m136). Epilogue transposes via LDS for ushort4 stores.
template <bool BF16OUT>
__global__ __launch_bounds__(256) void gemm_kernel(
    const float* __restrict__ x, const float* __restrict__ W,
    const float* __restrict__ b, void* __restrict__ outv, int N) {
    __shared__ unsigned short lds[2 * 64 * 136];   // xb [64][136] | Wb [64][136]
    const int t = threadIdx.x;
    const int w = t >> 6;
    const int lane = t & 63;
    const int row0 = blockIdx.x * 64;

    #pragma unroll
    for (int it = 0; it < 8; ++it) {               // x -> bf16 LDS
        int flat = it * 256 + t;                   // 0..2047 float4s
        int r = flat >> 5, c = flat & 31;
        float4 v = make_float4(0.f, 0.f, 0.f, 0.f);
        if (row0 + r < N) v = ((const float4*)x)[(size_t)(row0 + r) * 32 + c];
        ushort4 u = { f2bf(v.x), f2bf(v.y), f2bf(v.z), f2bf(v.w) };
        *(ushort4*)&lds[r * 136 + c * 4] = u;
    }
    #pragma unroll
    for (int it = 0; it < 8; ++it) {               // W -> bf16 LDS (o-major)
        int flat = it * 256 + t;
        int o = flat >> 5, c = flat & 31;
        float4 v = ((const float4*)W)[(size_t)o * 32 + c];
        ushort4 u = { f2bf(v.x), f2bf(v.y), f2bf(v.z), f2bf(v.w) };
        *(ushort4*)&lds[64 * 136 + o * 136 + c * 4] = u;
    }
    __syncthreads();

    const int m = lane & 15;                       // A row within tile / D col
    const int quad = lane >> 4;
    f32x4 acc[4] = {};                             // 4 o-tiles
    #pragma unroll
    for (int kb = 0; kb < 4; ++kb) {
        bf16x8 af = *(const bf16x8*)&lds[(w * 16 + m) * 136 + kb * 32 + quad * 8];
        #pragma unroll
        for (int ot = 0; ot < 4; ++ot) {
            bf16x8 bf = *(const bf16x8*)&lds[64 * 136 + (ot * 16 + m) * 136 + kb * 32 + quad * 8];
            acc[ot] = __builtin_amdgcn_mfma_f32_16x16x32_bf16(af, bf, acc[ot], 0, 0, 0);
        }
    }

    float bv[4];
    #pragma unroll
    for (int ot = 0; ot < 4; ++ot) bv[ot] = b[ot * 16 + m];

    __syncthreads();                               // before LDS reuse
    if (BF16OUT) {
        // D layout: col = lane&15, row = quad*4+reg (m89-verified). obuf stride 72.
        #pragma unroll
        for (int ot = 0; ot < 4; ++ot)
            #pragma unroll
            for (int reg = 0; reg < 4; ++reg)
                lds[(w * 16 + quad * 4 + reg) * 72 + ot * 16 + m] = f2bf(acc[ot][reg] + bv[ot]);
        __syncthreads();
        #pragma unroll
        for (int it = 0; it < 4; ++it) {
            int flat = it * 256 + t;               // 0..1023 ushort4s
            int r = flat >> 4, c4 = flat & 15;
            if (row0 + r < N)
                *(ushort4*)((unsigned short*)outv + (size_t)(row0 + r) * 64 + c4 * 4)
                    = *(ushort4*)&lds[r * 72 + c4 * 4];
        }
    } else {
        #pragma unroll
        for (int ot = 0; ot < 4; ++ot)
            #pragma unroll
            for (int reg = 0; reg < 4; ++reg) {
                int rr = row0 + w * 16 + quad * 4 + reg;
                if (rr < N) ((float*)outv)[(size_t)rr * 64 + ot * 16 + m] = acc[ot][reg] + bv[ot];
            }
    }
}

// ---------------- Phase 1: bucket histogram (bucket = row >> 8), LDS-aggregated ------------
__global__ __launch_bounds__(256) void bhist_kernel(const int* __restrict__ rowi,
                                                    int* __restrict__ bcnt, int E) {
    __shared__ int cnt[256];
    int t = threadIdx.x;
    cnt[t] = 0;
    __syncthreads();
    for (int e = blockIdx.x * 256 + t; e < E; e += gridDim.x * 256)
        atomicAdd(&cnt[rowi[e] >> 8], 1);
    __syncthreads();
    if (cnt[t] > 0) atomicAdd(&bcnt[t], cnt[t]);
}

// ---------------- Phase 2: scan bucket counts -> bases & cursors (1 block) ----------------
__global__ __launch_bounds__(256) void bscan_kernel(const int* __restrict__ bcnt,
                                                    int* __restrict__ bbase,
                                                    int* __restrict__ bcursor,
                                                    int* __restrict__ rowptr,
                                                    int nb, int N, int E) {
    int t = threadIdx.x;
    int v = (t < nb) ? bcnt[t] : 0;
    int lane = t & 63, w = t >> 6;
    int sum = v;
    #pragma unroll
    for (int off = 1; off < 64; off <<= 1) {
        int x = __shfl_up(sum, off, 64);
        if (lane >= off) sum += x;
    }
    __shared__ int wsum[4];
    if (lane == 63) wsum[w] = sum;
    __syncthreads();
    int woff = 0;
    for (int i = 0; i < w; ++i) woff += wsum[i];
    int excl = sum + woff - v;
    if (t <= nb) bbase[t] = excl;
    if (t < nb)  bcursor[t] = excl;
    if (t == 0)  rowptr[N] = E;
}

// ---------------- Phase 3: bin edges into bucket segments (8B recs, chunked writes) --------
__global__ __launch_bounds__(256) void bin_kernel(
    const int* __restrict__ rowi, const int* __restrict__ coli,
    const float* __restrict__ attr, int* __restrict__ bcursor,
    unsigned long long* __restrict__ tmp, int E) {
    __shared__ int cnt[256];
    __shared__ int cur[256];
    __shared__ int gbase[256];
    int t = threadIdx.x;
    int e0 = blockIdx.x * EPB;
    cnt[t] = 0;
    cur[t] = 0;
    __syncthreads();
    int myrow[16];
    #pragma unroll
    for (int i = 0; i < 16; ++i) {
        int e = e0 + i * 256 + t;
        myrow[i] = (e < E) ? rowi[e] : -1;
        if (myrow[i] >= 0) atomicAdd(&cnt[myrow[i] >> 8], 1);
    }
    __syncthreads();
    if (cnt[t] > 0) gbase[t] = atomicAdd(&bcursor[t], cnt[t]);
    __syncthreads();
    #pragma unroll
    for (int i = 0; i < 16; ++i) {
        int e = e0 + i * 256 + t;
        if (myrow[i] >= 0) {
            int b = myrow[i] >> 8;
            int rank = atomicAdd(&cur[b], 1);
            unsigned long long rec = ((unsigned long long)(myrow[i] & 255) << 32)
                                   | ((unsigned int)coli[e] << 16)
                                   | (unsigned int)f2bf(attr[e]);
            tmp[(size_t)gbase[b] + rank] = rec;
        }
    }
}

// ---------------- Phase 4: per-bucket sort -> scv + rowptr (L2-window-local) ---------------
__global__ __launch_bounds__(256) void bsort_kernel(
    const unsigned long long* __restrict__ tmp, const int* __restrict__ bbase,
    unsigned int* __restrict__ scv, int* __restrict__ rowptr, int N) {
    __shared__ int cnt[256];
    __shared__ int cur[256];
    __shared__ int wsum[4];
    int t = threadIdx.x, b = blockIdx.x;
    int seg = bbase[b], segend = bbase[b + 1];
    cnt[t] = 0;
    __syncthreads();
    for (int i = seg + t; i < segend; i += 256)
        atomicAdd(&cnt[(int)(tmp[i] >> 32)], 1);
    __syncthreads();
    int v = cnt[t];
    int lane = t & 63, w = t >> 6;
    int sum = v;
    #pragma unroll
    for (int off = 1; off < 64; off <<= 1) {
        int x = __shfl_up(sum, off, 64);
        if (lane >= off) sum += x;
    }
    if (lane == 63) wsum[w] = sum;
    __syncthreads();
    int woff = 0;
    for (int i = 0; i < w; ++i) woff += wsum[i];
    int excl = sum + woff - v;
    int gidx = b * 256 + t;
    if (gidx <= N) rowptr[gidx] = seg + excl;
    cur[t] = excl;
    __syncthreads();
    for (int i = seg + t; i < segend; i += 256) {
        unsigned long long rec = tmp[i];
        int rl = (int)(rec >> 32);
        int pos = atomicAdd(&cur[rl], 1);
        scv[(size_t)seg + pos] = (unsigned int)rec;
    }
}

// ---------------- SPMM (CSR): wave per row, PAIRED edges ----------------
// Lanes 0-31 process edge 2p, lanes 32-63 edge 2p+1; each lane covers a feature PAIR
// via one 4B load -> gather instruction count halved vs R6 (2B/lane). Cross-half
// reduction via shfl_xor(32). Tail pairs padded with rec=0 (w=+0.0, gathers row 0).
template <bool BF16OUT>
__global__ __launch_bounds__(256) void spmm_csr_kernel(
    const int* __restrict__ rowptr, const unsigned int* __restrict__ scv,
    const unsigned int* __restrict__ in32, void* __restrict__ outv, int N) {
    int wid = (blockIdx.x * 256 + threadIdx.x) >> 6;
    int lane = threadIdx.x & 63;
    if (wid >= N) return;
    wid = __builtin_amdgcn_readfirstlane(wid);
    int beg = rowptr[wid], end = rowptr[wid + 1];
    int half = lane >> 5;
    int lh = lane & 31;
    float accx = 0.f, accy = 0.f;
    int e = beg;
    for (; e + 16 <= end; e += 16) {
        unsigned int rec[16];
        #pragma unroll
        for (int i = 0; i < 16; ++i) rec[i] = scv[e + i];   // uniform -> s_load
        unsigned int xp[8]; float wv[8];
        #pragma unroll
        for (int p = 0; p < 8; ++p) {
            unsigned int r = half ? rec[2 * p + 1] : rec[2 * p];
            wv[p] = __uint_as_float(r << 16);
            xp[p] = in32[(size_t)(r >> 16) * 32 + lh];      // 8 gathers in flight
        }
        #pragma unroll
        for (int p = 0; p < 8; ++p) {
            accx = fmaf(wv[p], __uint_as_float(xp[p] << 16), accx);
            accy = fmaf(wv[p], __uint_as_float(xp[p] & 0xffff0000u), accy);
        }
    }
    for (; e < end; e += 2) {
        unsigned int rA = scv[e];
        unsigned int rB = (e + 1 < end) ? scv[e + 1] : 0u;
        unsigned int r = half ? rB : rA;
        float w = __uint_as_float(r << 16);
        unsigned int xpv = in32[(size_t)(r >> 16) * 32 + lh];
        accx = fmaf(w, __uint_as_float(xpv << 16), accx);
        accy = fmaf(w, __uint_as_float(xpv & 0xffff0000u), accy);
    }
    accx += __shfl_xor(accx, 32, 64);
    accy += __shfl_xor(accy, 32, 64);
    if (half == 0) {
        if (BF16OUT) {
            unsigned int o = (unsigned int)f2bf(accx) | ((unsigned int)f2bf(accy) << 16);
            ((unsigned int*)outv)[(size_t)wid * 32 + lh] = o;
        } else {
            ((float2*)outv)[(size_t)wid * 32 + lh] = make_float2(accx, accy);
        }
    }
}

// ---------------- fallback SPMM (fp32 atomics) if ws too small ----------------
__global__ __launch_bounds__(256) void spmm_atomic_kernel(
    const int* __restrict__ rowi, const int* __restrict__ coli,
    const float* __restrict__ attr, const float* __restrict__ in,
    float* __restrict__ out, int E) {
    int tid = blockIdx.x * 256 + threadIdx.x;
    int e = tid >> 6;
    int lane = tid & 63;
    if (e >= E) return;
    int r = rowi[e];
    int c = coli[e];
    float w = attr[e];
    float v = in[(size_t)c * OUT_F + lane];
    atomicAdd(&out[(size_t)r * OUT_F + lane], w * v);
}

extern "C" void kernel_launch(void* const* d_in, const int* in_sizes, int n_in,
                              void* d_out, int out_size, void* d_ws, size_t ws_size,
                              hipStream_t stream) {
    const float* x    = (const float*)d_in[0];
    const int*   ei   = (const int*)d_in[1];    // [2, E] int32 (confirmed R1)
    const float* attr = (const float*)d_in[2];
    const float* W    = (const float*)d_in[3];
    const float* b    = (const float*)d_in[4];
    float* out = (float*)d_out;

    const int N = in_sizes[0] / IN_F;   // 50000
    const int E = in_sizes[2];          // 800000
    const int* rowi = ei;
    const int* coli = ei + E;

    const size_t obytes_f  = (size_t)N * OUT_F * sizeof(float);
    const size_t obytes_bf = (size_t)N * OUT_F * sizeof(unsigned short);
    const int nb = (N + 255) / 256;     // 196 buckets

    // ---- ws layout (tmp overlays bufB: tmp dead before spmm round 1 writes bufB) ----
    char* wp = (char*)d_ws;
    size_t off = 0;
    auto alloc = [&](size_t bytes) { char* p = wp + off; off += (bytes + 255) & ~(size_t)255; return p; };
    unsigned short* bufA = (unsigned short*)alloc(obytes_bf);            // bf16 ping
    unsigned short* bufB = (unsigned short*)alloc((size_t)E * 8);        // bf16 pong / tmp overlay
    unsigned long long* tmp = (unsigned long long*)bufB;
    int* rowptr  = (int*)alloc((size_t)(N + 1) * 4);
    int* bcnt    = (int*)alloc(260 * 4);
    int* bbase   = (int*)alloc(260 * 4);
    int* bcursor = (int*)alloc(260 * 4);
    unsigned int* scv = (unsigned int*)alloc((size_t)E * 4);
    const bool csr_ok = (off <= ws_size) && (N <= 65280) && ((size_t)E * 8 >= obytes_bf);

    const int gemm_blocks = (N + 63) / 64;
    const int sb = (N * 64 + 255) / 256;

    if (csr_ok) {
        gemm_kernel<true><<<gemm_blocks, 256, 0, stream>>>(x, W, b, bufA, N);

        // ---- build row-sorted packed CSR via 2-phase bucketed counting sort ----
        hipMemsetAsync(bcnt, 0, 260 * 4, stream);
        bhist_kernel<<<512, 256, 0, stream>>>(rowi, bcnt, E);
        bscan_kernel<<<1, 256, 0, stream>>>(bcnt, bbase, bcursor, rowptr, nb, N, E);
        bin_kernel<<<(E + EPB - 1) / EPB, 256, 0, stream>>>(rowi, coli, attr, bcursor, tmp, E);
        bsort_kernel<<<nb, 256, 0, stream>>>(tmp, bbase, scv, rowptr, N);

        // ---- 3 rounds: bf16 -> bf16 -> bf16 -> fp32(d_out) ----
        spmm_csr_kernel<true ><<<sb, 256, 0, stream>>>(rowptr, scv, (const unsigned int*)bufA, bufB, N);
        spmm_csr_kernel<true ><<<sb, 256, 0, stream>>>(rowptr, scv, (const unsigned int*)bufB, bufA, N);
        spmm_csr_kernel<false><<<sb, 256, 0, stream>>>(rowptr, scv, (const unsigned int*)bufA, out, N);
    } else {
        // fallback: fp32 edge-parallel atomics, needs only one fp32 buffer
        float* ws0 = (float*)d_ws;
        gemm_kernel<false><<<gemm_blocks, 256, 0, stream>>>(x, W, b, ws0, N);
        const int spmm_blocks = (E * 64 + 255) / 256;
        hipMemsetAsync(out, 0, obytes_f, stream);
        spmm_atomic_kernel<<<spmm_blocks, 256, 0, stream>>>(rowi, coli, attr, ws0, out, E);
        hipMemsetAsync(ws0, 0, obytes_f, stream);
        spmm_atomic_kernel<<<spmm_blocks, 256, 0, stream>>>(rowi, coli, attr, out, ws0, E);
        hipMemsetAsync(out, 0, obytes_f, stream);
        spmm_atomic_kernel<<<spmm_blocks, 256, 0, stream>>>(rowi, coli, attr, ws0, out, E);
    }
}

// Round 8
// 213.060 us; speedup vs baseline: 1.3102x; 1.3102x over previous
//
#include <hip/hip_runtime.h>

#define IN_F   128
#define OUT_F  64
#define EPB    4096  // edges per bin block

typedef __attribute__((ext_vector_type(8))) short bf16x8;
typedef __attribute__((ext_vector_type(4))) float f32x4;

// ---- bf16 helpers (RNE) ----
__device__ __forceinline__ unsigned short f2bf(float f) {
    unsigned int u = __float_as_uint(f);
    u += 0x7fffu + ((u >> 16) & 1u);
    return (unsigned short)(u >> 16);
}
__device__ __forceinline__ float bf2f(unsigned short h) {
    return __uint_as_float(((unsigned int)h) << 16);
}

// ---------------- GEMM via MFMA bf16 (R7, kept) ----------------
template <bool BF16OUT>
__global__ __launch_bounds__(256) void gemm_kernel(
    const float* __restrict__ x, const float* __restrict__ W,
    const float* __restrict__ b, void* __restrict__ outv, int N) {
    __shared__ unsigned short lds[2 * 64 * 136];   // xb [64][136] | Wb [64][136]
    const int t = threadIdx.x;
    const int w = t >> 6;
    const int lane = t & 63;
    const int row0 = blockIdx.x * 64;

    #pragma unroll
    for (int it = 0; it < 8; ++it) {               // x -> bf16 LDS
        int flat = it * 256 + t;
        int r = flat >> 5, c = flat & 31;
        float4 v = make_float4(0.f, 0.f, 0.f, 0.f);
        if (row0 + r < N) v = ((const float4*)x)[(size_t)(row0 + r) * 32 + c];
        ushort4 u = { f2bf(v.x), f2bf(v.y), f2bf(v.z), f2bf(v.w) };
        *(ushort4*)&lds[r * 136 + c * 4] = u;
    }
    #pragma unroll
    for (int it = 0; it < 8; ++it) {               // W -> bf16 LDS (o-major)
        int flat = it * 256 + t;
        int o = flat >> 5, c = flat & 31;
        float4 v = ((const float4*)W)[(size_t)o * 32 + c];
        ushort4 u = { f2bf(v.x), f2bf(v.y), f2bf(v.z), f2bf(v.w) };
        *(ushort4*)&lds[64 * 136 + o * 136 + c * 4] = u;
    }
    __syncthreads();

    const int m = lane & 15;
    const int quad = lane >> 4;
    f32x4 acc[4] = {};
    #pragma unroll
    for (int kb = 0; kb < 4; ++kb) {
        bf16x8 af = *(const bf16x8*)&lds[(w * 16 + m) * 136 + kb * 32 + quad * 8];
        #pragma unroll
        for (int ot = 0; ot < 4; ++ot) {
            bf16x8 bf = *(const bf16x8*)&lds[64 * 136 + (ot * 16 + m) * 136 + kb * 32 + quad * 8];
            acc[ot] = __builtin_amdgcn_mfma_f32_16x16x32_bf16(af, bf, acc[ot], 0, 0, 0);
        }
    }

    float bv[4];
    #pragma unroll
    for (int ot = 0; ot < 4; ++ot) bv[ot] = b[ot * 16 + m];

    __syncthreads();
    if (BF16OUT) {
        #pragma unroll
        for (int ot = 0; ot < 4; ++ot)
            #pragma unroll
            for (int reg = 0; reg < 4; ++reg)
                lds[(w * 16 + quad * 4 + reg) * 72 + ot * 16 + m] = f2bf(acc[ot][reg] + bv[ot]);
        __syncthreads();
        #pragma unroll
        for (int it = 0; it < 4; ++it) {
            int flat = it * 256 + t;
            int r = flat >> 4, c4 = flat & 15;
            if (row0 + r < N)
                *(ushort4*)((unsigned short*)outv + (size_t)(row0 + r) * 64 + c4 * 4)
                    = *(ushort4*)&lds[r * 72 + c4 * 4];
        }
    } else {
        #pragma unroll
        for (int ot = 0; ot < 4; ++ot)
            #pragma unroll
            for (int reg = 0; reg < 4; ++reg) {
                int rr = row0 + w * 16 + quad * 4 + reg;
                if (rr < N) ((float*)outv)[(size_t)rr * 64 + ot * 16 + m] = acc[ot][reg] + bv[ot];
            }
    }
}

// ---------------- Phase 1: bucket histogram ----------------
__global__ __launch_bounds__(256) void bhist_kernel(const int* __restrict__ rowi,
                                                    int* __restrict__ bcnt, int E) {
    __shared__ int cnt[256];
    int t = threadIdx.x;
    cnt[t] = 0;
    __syncthreads();
    for (int e = blockIdx.x * 256 + t; e < E; e += gridDim.x * 256)
        atomicAdd(&cnt[rowi[e] >> 8], 1);
    __syncthreads();
    if (cnt[t] > 0) atomicAdd(&bcnt[t], cnt[t]);
}

// ---------------- Phase 2: bucket scan ----------------
__global__ __launch_bounds__(256) void bscan_kernel(const int* __restrict__ bcnt,
                                                    int* __restrict__ bbase,
                                                    int* __restrict__ bcursor,
                                                    int* __restrict__ rowptr,
                                                    int nb, int N, int E) {
    int t = threadIdx.x;
    int v = (t < nb) ? bcnt[t] : 0;
    int lane = t & 63, w = t >> 6;
    int sum = v;
    #pragma unroll
    for (int off = 1; off < 64; off <<= 1) {
        int x = __shfl_up(sum, off, 64);
        if (lane >= off) sum += x;
    }
    __shared__ int wsum[4];
    if (lane == 63) wsum[w] = sum;
    __syncthreads();
    int woff = 0;
    for (int i = 0; i < w; ++i) woff += wsum[i];
    int excl = sum + woff - v;
    if (t <= nb) bbase[t] = excl;
    if (t < nb)  bcursor[t] = excl;
    if (t == 0)  rowptr[N] = E;
}

// ---------------- Phase 3: bin edges (8B recs, chunked writes) ----------------
__global__ __launch_bounds__(256) void bin_kernel(
    const int* __restrict__ rowi, const int* __restrict__ coli,
    const float* __restrict__ attr, int* __restrict__ bcursor,
    unsigned long long* __restrict__ tmp, int E) {
    __shared__ int cnt[256];
    __shared__ int cur[256];
    __shared__ int gbase[256];
    int t = threadIdx.x;
    int e0 = blockIdx.x * EPB;
    cnt[t] = 0;
    cur[t] = 0;
    __syncthreads();
    int myrow[16];
    #pragma unroll
    for (int i = 0; i < 16; ++i) {
        int e = e0 + i * 256 + t;
        myrow[i] = (e < E) ? rowi[e] : -1;
        if (myrow[i] >= 0) atomicAdd(&cnt[myrow[i] >> 8], 1);
    }
    __syncthreads();
    if (cnt[t] > 0) gbase[t] = atomicAdd(&bcursor[t], cnt[t]);
    __syncthreads();
    #pragma unroll
    for (int i = 0; i < 16; ++i) {
        int e = e0 + i * 256 + t;
        if (myrow[i] >= 0) {
            int b = myrow[i] >> 8;
            int rank = atomicAdd(&cur[b], 1);
            unsigned long long rec = ((unsigned long long)(myrow[i] & 255) << 32)
                                   | ((unsigned int)coli[e] << 16)
                                   | (unsigned int)f2bf(attr[e]);
            tmp[(size_t)gbase[b] + rank] = rec;
        }
    }
}

// ---------------- Phase 4: per-bucket sort -> scv + rowptr ----------------
__global__ __launch_bounds__(256) void bsort_kernel(
    const unsigned long long* __restrict__ tmp, const int* __restrict__ bbase,
    unsigned int* __restrict__ scv, int* __restrict__ rowptr, int N) {
    __shared__ int cnt[256];
    __shared__ int cur[256];
    __shared__ int wsum[4];
    int t = threadIdx.x, b = blockIdx.x;
    int seg = bbase[b], segend = bbase[b + 1];
    cnt[t] = 0;
    __syncthreads();
    for (int i = seg + t; i < segend; i += 256)
        atomicAdd(&cnt[(int)(tmp[i] >> 32)], 1);
    __syncthreads();
    int v = cnt[t];
    int lane = t & 63, w = t >> 6;
    int sum = v;
    #pragma unroll
    for (int off = 1; off < 64; off <<= 1) {
        int x = __shfl_up(sum, off, 64);
        if (lane >= off) sum += x;
    }
    if (lane == 63) wsum[w] = sum;
    __syncthreads();
    int woff = 0;
    for (int i = 0; i < w; ++i) woff += wsum[i];
    int excl = sum + woff - v;
    int gidx = b * 256 + t;
    if (gidx <= N) rowptr[gidx] = seg + excl;
    cur[t] = excl;
    __syncthreads();
    for (int i = seg + t; i < segend; i += 256) {
        unsigned long long rec = tmp[i];
        int rl = (int)(rec >> 32);
        int pos = atomicAdd(&cur[rl], 1);
        scv[(size_t)seg + pos] = (unsigned int)rec;
    }
}

// ---------------- SPMM (CSR): wave per row, PAIRED edges, constant-indexed arrays --------
// R7 regression root-cause: rec[2p+half] (dynamic index) -> PromoteAlloca put the array
// in LDS (LDS_Block_Size=16384, 8.9M bank conflicts). Here ALL array subscripts are the
// unrolled induction var; `half` lives in address arithmetic -> SROA keeps regs.
template <bool BF16OUT>
__global__ __launch_bounds__(256) void spmm_csr_kernel(
    const int* __restrict__ rowptr, const unsigned int* __restrict__ scv,
    const unsigned int* __restrict__ in32, void* __restrict__ outv, int N) {
    int wid = (blockIdx.x * 256 + threadIdx.x) >> 6;
    int lane = threadIdx.x & 63;
    if (wid >= N) return;
    wid = __builtin_amdgcn_readfirstlane(wid);
    int beg = rowptr[wid], end = rowptr[wid + 1];
    const int half = lane >> 5;      // which edge of the pair
    const int lh = lane & 31;        // feature-pair index (2 bf16 per uint)
    float accx = 0.f, accy = 0.f;
    int e = beg;
    for (; e + 16 <= end; e += 16) {
        unsigned int rec[8];
        #pragma unroll
        for (int p = 0; p < 8; ++p) rec[p] = scv[e + 2 * p + half];    // const idx p
        unsigned int xp[8];
        #pragma unroll
        for (int p = 0; p < 8; ++p) xp[p] = in32[(size_t)(rec[p] >> 16) * 32 + lh];
        #pragma unroll
        for (int p = 0; p < 8; ++p) {
            float wv = __uint_as_float(rec[p] << 16);
            accx = fmaf(wv, __uint_as_float(xp[p] << 16), accx);
            accy = fmaf(wv, __uint_as_float(xp[p] & 0xffff0000u), accy);
        }
    }
    for (; e + 2 <= end; e += 2) {
        unsigned int r = scv[e + half];
        float wv = __uint_as_float(r << 16);
        unsigned int xv = in32[(size_t)(r >> 16) * 32 + lh];
        accx = fmaf(wv, __uint_as_float(xv << 16), accx);
        accy = fmaf(wv, __uint_as_float(xv & 0xffff0000u), accy);
    }
    if (e < end) {                    // odd last edge: half 1 uses zero-record (w=+0)
        unsigned int r = (half == 0) ? scv[e] : 0u;
        float wv = __uint_as_float(r << 16);
        unsigned int xv = in32[(size_t)(r >> 16) * 32 + lh];
        accx = fmaf(wv, __uint_as_float(xv << 16), accx);
        accy = fmaf(wv, __uint_as_float(xv & 0xffff0000u), accy);
    }
    accx += __shfl_xor(accx, 32, 64);
    accy += __shfl_xor(accy, 32, 64);
    if (half == 0) {
        if (BF16OUT) {
            unsigned int o = (unsigned int)f2bf(accx) | ((unsigned int)f2bf(accy) << 16);
            ((unsigned int*)outv)[(size_t)wid * 32 + lh] = o;
        } else {
            ((float2*)outv)[(size_t)wid * 32 + lh] = make_float2(accx, accy);
        }
    }
}

// ---------------- fallback SPMM (fp32 atomics) ----------------
__global__ __launch_bounds__(256) void spmm_atomic_kernel(
    const int* __restrict__ rowi, const int* __restrict__ coli,
    const float* __restrict__ attr, const float* __restrict__ in,
    float* __restrict__ out, int E) {
    int tid = blockIdx.x * 256 + threadIdx.x;
    int e = tid >> 6;
    int lane = tid & 63;
    if (e >= E) return;
    int r = rowi[e];
    int c = coli[e];
    float w = attr[e];
    float v = in[(size_t)c * OUT_F + lane];
    atomicAdd(&out[(size_t)r * OUT_F + lane], w * v);
}

extern "C" void kernel_launch(void* const* d_in, const int* in_sizes, int n_in,
                              void* d_out, int out_size, void* d_ws, size_t ws_size,
                              hipStream_t stream) {
    const float* x    = (const float*)d_in[0];
    const int*   ei   = (const int*)d_in[1];    // [2, E] int32 (confirmed R1)
    const float* attr = (const float*)d_in[2];
    const float* W    = (const float*)d_in[3];
    const float* b    = (const float*)d_in[4];
    float* out = (float*)d_out;

    const int N = in_sizes[0] / IN_F;   // 50000
    const int E = in_sizes[2];          // 800000
    const int* rowi = ei;
    const int* coli = ei + E;

    const size_t obytes_f  = (size_t)N * OUT_F * sizeof(float);
    const size_t obytes_bf = (size_t)N * OUT_F * sizeof(unsigned short);
    const int nb = (N + 255) / 256;     // 196 buckets

    // ---- ws layout (tmp overlays bufB: tmp dead before spmm round 1 writes bufB) ----
    char* wp = (char*)d_ws;
    size_t off = 0;
    auto alloc = [&](size_t bytes) { char* p = wp + off; off += (bytes + 255) & ~(size_t)255; return p; };
    unsigned short* bufA = (unsigned short*)alloc(obytes_bf);            // bf16 ping
    unsigned short* bufB = (unsigned short*)alloc((size_t)E * 8);        // bf16 pong / tmp overlay
    unsigned long long* tmp = (unsigned long long*)bufB;
    int* rowptr  = (int*)alloc((size_t)(N + 1) * 4);
    int* bcnt    = (int*)alloc(260 * 4);
    int* bbase   = (int*)alloc(260 * 4);
    int* bcursor = (int*)alloc(260 * 4);
    unsigned int* scv = (unsigned int*)alloc((size_t)E * 4);
    const bool csr_ok = (off <= ws_size) && (N <= 65280) && ((size_t)E * 8 >= obytes_bf);

    const int gemm_blocks = (N + 63) / 64;
    const int sb = (N * 64 + 255) / 256;

    if (csr_ok) {
        gemm_kernel<true><<<gemm_blocks, 256, 0, stream>>>(x, W, b, bufA, N);

        // ---- build row-sorted packed CSR via 2-phase bucketed counting sort ----
        hipMemsetAsync(bcnt, 0, 260 * 4, stream);
        bhist_kernel<<<512, 256, 0, stream>>>(rowi, bcnt, E);
        bscan_kernel<<<1, 256, 0, stream>>>(bcnt, bbase, bcursor, rowptr, nb, N, E);
        bin_kernel<<<(E + EPB - 1) / EPB, 256, 0, stream>>>(rowi, coli, attr, bcursor, tmp, E);
        bsort_kernel<<<nb, 256, 0, stream>>>(tmp, bbase, scv, rowptr, N);

        // ---- 3 rounds: bf16 -> bf16 -> bf16 -> fp32(d_out) ----
        spmm_csr_kernel<true ><<<sb, 256, 0, stream>>>(rowptr, scv, (const unsigned int*)bufA, bufB, N);
        spmm_csr_kernel<true ><<<sb, 256, 0, stream>>>(rowptr, scv, (const unsigned int*)bufB, bufA, N);
        spmm_csr_kernel<false><<<sb, 256, 0, stream>>>(rowptr, scv, (const unsigned int*)bufA, out, N);
    } else {
        // fallback: fp32 edge-parallel atomics, needs only one fp32 buffer
        float* ws0 = (float*)d_ws;
        gemm_kernel<false><<<gemm_blocks, 256, 0, stream>>>(x, W, b, ws0, N);
        const int spmm_blocks = (E * 64 + 255) / 256;
        hipMemsetAsync(out, 0, obytes_f, stream);
        spmm_atomic_kernel<<<spmm_blocks, 256, 0, stream>>>(rowi, coli, attr, ws0, out, E);
        hipMemsetAsync(ws0, 0, obytes_f, stream);
        spmm_atomic_kernel<<<spmm_blocks, 256, 0, stream>>>(rowi, coli, attr, out, ws0, E);
        hipMemsetAsync(out, 0, obytes_f, stream);
        spmm_atomic_kernel<<<spmm_blocks, 256, 0, stream>>>(rowi, coli, attr, ws0, out, E);
    }
}

// Round 9
// 203.244 us; speedup vs baseline: 1.3735x; 1.0483x over previous
//
#include <hip/hip_runtime.h>

#define IN_F   128
#define OUT_F  64
#define EPB    4096  // edges per bin block

typedef __attribute__((ext_vector_type(8))) short bf16x8;
typedef __attribute__((ext_vector_type(4))) float f32x4;

// ---- bf16 helpers (RNE) ----
__device__ __forceinline__ unsigned short f2bf(float f) {
    unsigned int u = __float_as_uint(f);
    u += 0x7fffu + ((u >> 16) & 1u);
    return (unsigned short)(u >> 16);
}

// ---------------- GEMM via MFMA bf16 (R8) + folded rcnt zeroing ----------------
template <bool BF16OUT>
__global__ __launch_bounds__(256) void gemm_kernel(
    const float* __restrict__ x, const float* __restrict__ W,
    const float* __restrict__ b, void* __restrict__ outv, int N,
    int* __restrict__ rcnt, int Nr) {
    const int t = threadIdx.x;
    for (int i = blockIdx.x * 256 + t; i < Nr; i += gridDim.x * 256) rcnt[i] = 0;

    __shared__ unsigned short lds[2 * 64 * 136];   // xb [64][136] | Wb [64][136]
    const int w = t >> 6;
    const int lane = t & 63;
    const int row0 = blockIdx.x * 64;

    #pragma unroll
    for (int it = 0; it < 8; ++it) {               // x -> bf16 LDS
        int flat = it * 256 + t;
        int r = flat >> 5, c = flat & 31;
        float4 v = make_float4(0.f, 0.f, 0.f, 0.f);
        if (row0 + r < N) v = ((const float4*)x)[(size_t)(row0 + r) * 32 + c];
        ushort4 u = { f2bf(v.x), f2bf(v.y), f2bf(v.z), f2bf(v.w) };
        *(ushort4*)&lds[r * 136 + c * 4] = u;
    }
    #pragma unroll
    for (int it = 0; it < 8; ++it) {               // W -> bf16 LDS (o-major)
        int flat = it * 256 + t;
        int o = flat >> 5, c = flat & 31;
        float4 v = ((const float4*)W)[(size_t)o * 32 + c];
        ushort4 u = { f2bf(v.x), f2bf(v.y), f2bf(v.z), f2bf(v.w) };
        *(ushort4*)&lds[64 * 136 + o * 136 + c * 4] = u;
    }
    __syncthreads();

    const int m = lane & 15;
    const int quad = lane >> 4;
    f32x4 acc[4] = {};
    #pragma unroll
    for (int kb = 0; kb < 4; ++kb) {
        bf16x8 af = *(const bf16x8*)&lds[(w * 16 + m) * 136 + kb * 32 + quad * 8];
        #pragma unroll
        for (int ot = 0; ot < 4; ++ot) {
            bf16x8 bf = *(const bf16x8*)&lds[64 * 136 + (ot * 16 + m) * 136 + kb * 32 + quad * 8];
            acc[ot] = __builtin_amdgcn_mfma_f32_16x16x32_bf16(af, bf, acc[ot], 0, 0, 0);
        }
    }

    float bv[4];
    #pragma unroll
    for (int ot = 0; ot < 4; ++ot) bv[ot] = b[ot * 16 + m];

    __syncthreads();
    if (BF16OUT) {
        #pragma unroll
        for (int ot = 0; ot < 4; ++ot)
            #pragma unroll
            for (int reg = 0; reg < 4; ++reg)
                lds[(w * 16 + quad * 4 + reg) * 72 + ot * 16 + m] = f2bf(acc[ot][reg] + bv[ot]);
        __syncthreads();
        #pragma unroll
        for (int it = 0; it < 4; ++it) {
            int flat = it * 256 + t;
            int r = flat >> 4, c4 = flat & 15;
            if (row0 + r < N)
                *(ushort4*)((unsigned short*)outv + (size_t)(row0 + r) * 64 + c4 * 4)
                    = *(ushort4*)&lds[r * 72 + c4 * 4];
        }
    } else {
        #pragma unroll
        for (int ot = 0; ot < 4; ++ot)
            #pragma unroll
            for (int reg = 0; reg < 4; ++reg) {
                int rr = row0 + w * 16 + quad * 4 + reg;
                if (rr < N) ((float*)outv)[(size_t)rr * 64 + ot * 16 + m] = acc[ot][reg] + bv[ot];
            }
    }
}

// ---------------- hist: per-row counts + folded scv zeroing ----------------
__global__ __launch_bounds__(256) void hist_kernel(const int* __restrict__ rowi,
                                                   int* __restrict__ rcnt,
                                                   unsigned int* __restrict__ scv,
                                                   int scvcap, int E) {
    int gid = blockIdx.x * 256 + threadIdx.x;
    for (int i = gid; i < scvcap; i += gridDim.x * 256) scv[i] = 0u;  // pad slots = {col0, w=+0}
    if (gid < E) atomicAdd(&rcnt[rowi[gid]], 1);
}

// ---------------- rowscan: per-bucket dual scan (real deg + padded deg) -------------
// rowptr[gid] = block-LOCAL exclusive scan of pdeg (finalized in bsort);
// btotR/btotP = bucket totals (real / padded).
__global__ __launch_bounds__(256) void rowscan_kernel(const int* __restrict__ rcnt,
                                                      int* __restrict__ rowptr,
                                                      int* __restrict__ btotR,
                                                      int* __restrict__ btotP, int N) {
    int t = threadIdx.x, gid = blockIdx.x * 256 + t;
    int lane = t & 63, w = t >> 6;
    int d = (gid < N) ? rcnt[gid] : 0;
    int pd = (d + 15) & ~15;
    int sr = d, sp = pd;
    #pragma unroll
    for (int off = 1; off < 64; off <<= 1) {
        int a = __shfl_up(sr, off, 64), b = __shfl_up(sp, off, 64);
        if (lane >= off) { sr += a; sp += b; }
    }
    __shared__ int wr[4], wp[4];
    if (lane == 63) { wr[w] = sr; wp[w] = sp; }
    __syncthreads();
    int or_ = 0, op_ = 0;
    for (int i = 0; i < w; ++i) { or_ += wr[i]; op_ += wp[i]; }
    int inclR = sr + or_, inclP = sp + op_;
    if (gid < N) rowptr[gid] = inclP - pd;         // local exclusive (padded)
    if (t == 255) { btotR[blockIdx.x] = inclR; btotP[blockIdx.x] = inclP; }
}

// ---------------- bscan: scan bucket totals (1 block) ----------------
// bbaseR[b] = real-record segment base (tmp & scv real layout uses REAL scan for tmp);
// badd[b]  = padded base added to local rowptr in bsort; bcursor init = bbaseR.
__global__ __launch_bounds__(256) void bscan_kernel(const int* __restrict__ btotR,
                                                    const int* __restrict__ btotP,
                                                    int* __restrict__ bbaseR,
                                                    int* __restrict__ badd,
                                                    int* __restrict__ bcursor,
                                                    int* __restrict__ rowptr,
                                                    int nb, int N) {
    int t = threadIdx.x;
    int vr = (t < nb) ? btotR[t] : 0;
    int vp = (t < nb) ? btotP[t] : 0;
    int lane = t & 63, w = t >> 6;
    int sr = vr, sp = vp;
    #pragma unroll
    for (int off = 1; off < 64; off <<= 1) {
        int a = __shfl_up(sr, off, 64), b = __shfl_up(sp, off, 64);
        if (lane >= off) { sr += a; sp += b; }
    }
    __shared__ int wr[4], wp[4];
    if (lane == 63) { wr[w] = sr; wp[w] = sp; }
    __syncthreads();
    int or_ = 0, op_ = 0;
    for (int i = 0; i < w; ++i) { or_ += wr[i]; op_ += wp[i]; }
    int inclR = sr + or_, inclP = sp + op_;
    if (t < nb) {
        bbaseR[t] = inclR - vr;
        badd[t]   = inclP - vp;
        bcursor[t] = inclR - vr;
    }
    if (t == nb - 1) { bbaseR[nb] = inclR; rowptr[N] = inclP; }
}

// ---------------- bin: edges -> bucket segments of tmp (8B recs, chunked) -----------
__global__ __launch_bounds__(256) void bin_kernel(
    const int* __restrict__ rowi, const int* __restrict__ coli,
    const float* __restrict__ attr, int* __restrict__ bcursor,
    unsigned long long* __restrict__ tmp, int E) {
    __shared__ int cnt[256];
    __shared__ int cur[256];
    __shared__ int gbase[256];
    int t = threadIdx.x;
    int e0 = blockIdx.x * EPB;
    cnt[t] = 0;
    cur[t] = 0;
    __syncthreads();
    int myrow[16];
    #pragma unroll
    for (int i = 0; i < 16; ++i) {
        int e = e0 + i * 256 + t;
        myrow[i] = (e < E) ? rowi[e] : -1;
        if (myrow[i] >= 0) atomicAdd(&cnt[myrow[i] >> 8], 1);
    }
    __syncthreads();
    if (cnt[t] > 0) gbase[t] = atomicAdd(&bcursor[t], cnt[t]);
    __syncthreads();
    #pragma unroll
    for (int i = 0; i < 16; ++i) {
        int e = e0 + i * 256 + t;
        if (myrow[i] >= 0) {
            int b = myrow[i] >> 8;
            int rank = atomicAdd(&cur[b], 1);
            unsigned long long rec = ((unsigned long long)(myrow[i] & 255) << 32)
                                   | ((unsigned int)coli[e] << 16)
                                   | (unsigned int)f2bf(attr[e]);
            tmp[(size_t)gbase[b] + rank] = rec;
        }
    }
}

// ---------------- bsort: place recs at PADDED row offsets; finalize rowptr ----------
__global__ __launch_bounds__(256) void bsort_kernel(
    const unsigned long long* __restrict__ tmp, const int* __restrict__ bbaseR,
    const int* __restrict__ badd, unsigned int* __restrict__ scv,
    int* __restrict__ rowptr, int N) {
    __shared__ int cur[256];
    int t = threadIdx.x, b = blockIdx.x;
    int segR = bbaseR[b], segRend = bbaseR[b + 1];
    int pb = badd[b];
    int gidx = b * 256 + t;
    int fp = 0;
    if (gidx < N) {
        fp = pb + rowptr[gidx];          // final padded rowptr
        rowptr[gidx] = fp;
    }
    cur[t] = fp;
    __syncthreads();
    for (int i = segR + t; i < segRend; i += 256) {
        unsigned long long rec = tmp[i];
        int rl = (int)(rec >> 32);
        int pos = atomicAdd(&cur[rl], 1);
        scv[(size_t)pos] = (unsigned int)rec;    // pad slots stay 0 (pre-zeroed)
    }
}

// ---------------- SPMM: wave per row, paired edges, MAIN LOOP ONLY (rows padded to 16) ----
template <bool BF16OUT>
__global__ __launch_bounds__(256) void spmm_csr_kernel(
    const int* __restrict__ rowptr, const unsigned int* __restrict__ scv,
    const unsigned int* __restrict__ in32, void* __restrict__ outv, int N) {
    int wid = (blockIdx.x * 256 + threadIdx.x) >> 6;
    int lane = threadIdx.x & 63;
    if (wid >= N) return;
    wid = __builtin_amdgcn_readfirstlane(wid);
    int beg = rowptr[wid], end = rowptr[wid + 1];   // end-beg multiple of 16
    const int half = lane >> 5;
    const int lh = lane & 31;
    float accx = 0.f, accy = 0.f;
    for (int e = beg; e < end; e += 16) {
        unsigned int rec[8];
        #pragma unroll
        for (int p = 0; p < 8; ++p) rec[p] = scv[e + 2 * p + half];   // const-indexed
        unsigned int xp[8];
        #pragma unroll
        for (int p = 0; p < 8; ++p) xp[p] = in32[(size_t)(rec[p] >> 16) * 32 + lh];
        #pragma unroll
        for (int p = 0; p < 8; ++p) {
            float wv = __uint_as_float(rec[p] << 16);
            accx = fmaf(wv, __uint_as_float(xp[p] << 16), accx);
            accy = fmaf(wv, __uint_as_float(xp[p] & 0xffff0000u), accy);
        }
    }
    accx += __shfl_xor(accx, 32, 64);
    accy += __shfl_xor(accy, 32, 64);
    if (half == 0) {
        if (BF16OUT) {
            unsigned int o = (unsigned int)f2bf(accx) | ((unsigned int)f2bf(accy) << 16);
            ((unsigned int*)outv)[(size_t)wid * 32 + lh] = o;
        } else {
            ((float2*)outv)[(size_t)wid * 32 + lh] = make_float2(accx, accy);
        }
    }
}

// ---------------- fallback SPMM (fp32 atomics) ----------------
__global__ __launch_bounds__(256) void spmm_atomic_kernel(
    const int* __restrict__ rowi, const int* __restrict__ coli,
    const float* __restrict__ attr, const float* __restrict__ in,
    float* __restrict__ out, int E) {
    int tid = blockIdx.x * 256 + threadIdx.x;
    int e = tid >> 6;
    int lane = tid & 63;
    if (e >= E) return;
    int r = rowi[e];
    int c = coli[e];
    float w = attr[e];
    float v = in[(size_t)c * OUT_F + lane];
    atomicAdd(&out[(size_t)r * OUT_F + lane], w * v);
}

extern "C" void kernel_launch(void* const* d_in, const int* in_sizes, int n_in,
                              void* d_out, int out_size, void* d_ws, size_t ws_size,
                              hipStream_t stream) {
    const float* x    = (const float*)d_in[0];
    const int*   ei   = (const int*)d_in[1];    // [2, E] int32 (confirmed R1)
    const float* attr = (const float*)d_in[2];
    const float* W    = (const float*)d_in[3];
    const float* b    = (const float*)d_in[4];
    float* out = (float*)d_out;

    const int N = in_sizes[0] / IN_F;   // 50000
    const int E = in_sizes[2];          // 800000
    const int* rowi = ei;
    const int* coli = ei + E;

    const size_t obytes_f  = (size_t)N * OUT_F * sizeof(float);
    const size_t obytes_bf = (size_t)N * OUT_F * sizeof(unsigned short);
    const int nb = (N + 255) / 256;     // 196 buckets
    const int scvcap = E + 15 * N;      // worst-case padded record count

    // ---- ws layout (tmp overlays bufB; both dead/live disjoint) ----
    char* wp = (char*)d_ws;
    size_t off = 0;
    auto alloc = [&](size_t bytes) { char* p = wp + off; off += (bytes + 255) & ~(size_t)255; return p; };
    unsigned short* bufA = (unsigned short*)alloc(obytes_bf);            // bf16 ping
    size_t bufB_bytes = (size_t)E * 8 > obytes_bf ? (size_t)E * 8 : obytes_bf;
    unsigned short* bufB = (unsigned short*)alloc(bufB_bytes);           // bf16 pong / tmp overlay
    unsigned long long* tmp = (unsigned long long*)bufB;
    int* rowptr  = (int*)alloc((size_t)(N + 1) * 4);
    int* rcnt    = (int*)alloc((size_t)N * 4);
    int* btotR   = (int*)alloc(260 * 4);
    int* btotP   = (int*)alloc(260 * 4);
    int* bbaseR  = (int*)alloc(260 * 4);
    int* badd    = (int*)alloc(260 * 4);
    int* bcursor = (int*)alloc(260 * 4);
    unsigned int* scv = (unsigned int*)alloc((size_t)scvcap * 4);
    const bool csr_ok = (off <= ws_size) && (N <= 65535);

    const int gemm_blocks = (N + 63) / 64;
    const int eb = (E + 255) / 256;
    const int sb = (N * 64 + 255) / 256;

    if (csr_ok) {
        gemm_kernel<true><<<gemm_blocks, 256, 0, stream>>>(x, W, b, bufA, N, rcnt, N);

        // ---- build padded row-sorted CSR (9 launches total incl. gemm + 3 spmm) ----
        hist_kernel<<<eb, 256, 0, stream>>>(rowi, rcnt, scv, scvcap, E);
        rowscan_kernel<<<nb, 256, 0, stream>>>(rcnt, rowptr, btotR, btotP, N);
        bscan_kernel<<<1, 256, 0, stream>>>(btotR, btotP, bbaseR, badd, bcursor, rowptr, nb, N);
        bin_kernel<<<(E + EPB - 1) / EPB, 256, 0, stream>>>(rowi, coli, attr, bcursor, tmp, E);
        bsort_kernel<<<nb, 256, 0, stream>>>(tmp, bbaseR, badd, scv, rowptr, N);

        // ---- 3 rounds: bf16 -> bf16 -> bf16 -> fp32(d_out) ----
        spmm_csr_kernel<true ><<<sb, 256, 0, stream>>>(rowptr, scv, (const unsigned int*)bufA, bufB, N);
        spmm_csr_kernel<true ><<<sb, 256, 0, stream>>>(rowptr, scv, (const unsigned int*)bufB, bufA, N);
        spmm_csr_kernel<false><<<sb, 256, 0, stream>>>(rowptr, scv, (const unsigned int*)bufA, out, N);
    } else {
        // fallback: fp32 edge-parallel atomics
        float* ws0 = (float*)d_ws;
        int* dummy = (int*)((char*)d_ws + obytes_f);
        gemm_kernel<false><<<gemm_blocks, 256, 0, stream>>>(x, W, b, ws0, N, dummy, 0);
        const int spmm_blocks = (E * 64 + 255) / 256;
        hipMemsetAsync(out, 0, obytes_f, stream);
        spmm_atomic_kernel<<<spmm_blocks, 256, 0, stream>>>(rowi, coli, attr, ws0, out, E);
        hipMemsetAsync(ws0, 0, obytes_f, stream);
        spmm_atomic_kernel<<<spmm_blocks, 256, 0, stream>>>(rowi, coli, attr, out, ws0, E);
        hipMemsetAsync(out, 0, obytes_f, stream);
        spmm_atomic_kernel<<<spmm_blocks, 256, 0, stream>>>(rowi, coli, attr, ws0, out, E);
    }
}